// Round 1
// baseline (594.807 us; speedup 1.0000x reference)
//
#include <hip/hip_runtime.h>

#define NTOK 8192
#define DIM  512
#define MHID 2048
#define EHID 1024
#define NEXP 8

using half_t = _Float16;
typedef _Float16 f16x8 __attribute__((ext_vector_type(8)));
typedef float    f32x4 __attribute__((ext_vector_type(4)));

__device__ __forceinline__ float gelu_exact(float v) {
    return 0.5f * v * (1.0f + erff(v * 0.70710678118654752f));
}

__device__ __forceinline__ f16x8 f16x8_zero() {
    f16x8 v;
#pragma unroll
    for (int i = 0; i < 8; i++) v[i] = (_Float16)0.f;
    return v;
}

// all-threads-return block sum over 4 waves (256 threads)
__device__ __forceinline__ float block_sum4(float v, float* red, int tid) {
#pragma unroll
    for (int off = 32; off; off >>= 1) v += __shfl_down(v, off);
    if ((tid & 63) == 0) red[tid >> 6] = v;
    __syncthreads();
    float r = red[0] + red[1] + red[2] + red[3];
    __syncthreads();
    return r;
}

// ---------------- LN1 + fp16 hi/lo split ----------------
__global__ __launch_bounds__(256) void ln1_split_kernel(
    const float* __restrict__ x, const float* __restrict__ g, const float* __restrict__ b,
    half_t* __restrict__ xh, half_t* __restrict__ xl)
{
    const int row = blockIdx.x, tid = threadIdx.x;
    __shared__ float red[4];
    const size_t base = (size_t)row * DIM;
    float2 v = reinterpret_cast<const float2*>(x + base)[tid];
    float mean = block_sum4(v.x + v.y, red, tid) * (1.0f / DIM);
    float d0 = v.x - mean, d1 = v.y - mean;
    float var = block_sum4(d0 * d0 + d1 * d1, red, tid) * (1.0f / DIM);
    float rstd = rsqrtf(var + 1e-5f);
    int d = tid * 2;
    float y0 = d0 * rstd * g[d]     + b[d];
    float y1 = d1 * rstd * g[d + 1] + b[d + 1];
    half_t h0 = (half_t)y0, h1 = (half_t)y1;
    xh[base + d] = h0;  xh[base + d + 1] = h1;
    xl[base + d]     = (half_t)(y0 - (float)h0);
    xl[base + d + 1] = (half_t)(y1 - (float)h1);
}

// ---------------- x2 = x + h ; x3 = LN2(x2) + x2 (in place over h) ----------------
__global__ __launch_bounds__(256) void resid_ln2_kernel(
    const float* __restrict__ x, float* __restrict__ hio,
    const float* __restrict__ g, const float* __restrict__ b,
    half_t* __restrict__ x3h)
{
    const int row = blockIdx.x, tid = threadIdx.x;
    __shared__ float red[4];
    const size_t base = (size_t)row * DIM;
    float2 xv = reinterpret_cast<const float2*>(x + base)[tid];
    float2 hv = reinterpret_cast<float2*>(hio + base)[tid];
    float z0 = xv.x + hv.x, z1 = xv.y + hv.y;
    float mean = block_sum4(z0 + z1, red, tid) * (1.0f / DIM);
    float d0 = z0 - mean, d1 = z1 - mean;
    float var = block_sum4(d0 * d0 + d1 * d1, red, tid) * (1.0f / DIM);
    float rstd = rsqrtf(var + 1e-5f);
    int d = tid * 2;
    float y0 = d0 * rstd * g[d]     + b[d]     + z0;
    float y1 = d1 * rstd * g[d + 1] + b[d + 1] + z1;
    float2 o; o.x = y0; o.y = y1;
    reinterpret_cast<float2*>(hio + base)[tid] = o;
    x3h[base + d]     = (half_t)y0;
    x3h[base + d + 1] = (half_t)y1;
}

// ---------------- transpose [R][C] -> [C][R], cast to f16 (optional lo split) ----------------
__global__ void transpose_split_kernel(const float* __restrict__ in,
                                       half_t* __restrict__ oh, half_t* __restrict__ ol,
                                       int R, int C)
{
    __shared__ float t[32][33];
    const size_t mo = (size_t)blockIdx.z * (size_t)R * (size_t)C;
    const int c0 = blockIdx.x * 32, r0 = blockIdx.y * 32;
    const int tx = threadIdx.x, ty = threadIdx.y;
    for (int i = ty; i < 32; i += 8) t[i][tx] = in[mo + (size_t)(r0 + i) * C + c0 + tx];
    __syncthreads();
    for (int i = ty; i < 32; i += 8) {
        float v = t[tx][i];
        size_t o = mo + (size_t)(c0 + i) * R + r0 + tx;
        half_t h = (half_t)v;
        oh[o] = h;
        if (ol) ol[o] = (half_t)(v - (float)h);
    }
}

// ---------------- split-3 f16 MFMA GEMM: C = (Ah+Al)(Bh+Bl)^T approx ----------------
// A: [M][K] f16 hi/lo.  B: [Nc][K] f16 hi/lo (pre-transposed weights).
// EPI==1: gelu(acc+bias) -> split f16 hi/lo outs.  EPI==0: acc+bias -> f32 out.
template <int EPI>
__global__ __launch_bounds__(256) void gemm3_kernel(
    const half_t* __restrict__ A0, const half_t* __restrict__ A1,
    const half_t* __restrict__ B0, const half_t* __restrict__ B1,
    const float* __restrict__ bias,
    float* __restrict__ Cf, half_t* __restrict__ Ch, half_t* __restrict__ Cl,
    int M, int Nc, int K)
{
    __shared__ half_t As[128][40];
    __shared__ half_t Bs[128][40];
    const int m0 = blockIdx.x * 128, n0 = blockIdx.y * 128;
    const int tid = threadIdx.x;
    const int lane = tid & 63, wid = tid >> 6;
    const int wr = wid >> 1, wc = wid & 1;
    f32x4 acc[4][4];
#pragma unroll
    for (int i = 0; i < 4; i++)
#pragma unroll
        for (int j = 0; j < 4; j++)
#pragma unroll
            for (int q = 0; q < 4; q++) acc[i][j][q] = 0.f;

    const int sm = tid >> 1, sk = (tid & 1) * 16;
    const size_t aoff = (size_t)(m0 + sm) * K + sk;
    const size_t boff = (size_t)(n0 + sm) * K + sk;
    const int kk = (lane >> 4) * 8;
    const int fr = lane & 15;

#pragma unroll 1
    for (int term = 0; term < 3; ++term) {
        const half_t* Ap = (term == 1 ? A1 : A0) + aoff;
        const half_t* Bp = (term == 2 ? B1 : B0) + boff;
#pragma unroll 1
        for (int k0 = 0; k0 < K; k0 += 32) {
            __syncthreads();
            *(f16x8*)&As[sm][sk]     = *(const f16x8*)(Ap + k0);
            *(f16x8*)&As[sm][sk + 8] = *(const f16x8*)(Ap + k0 + 8);
            *(f16x8*)&Bs[sm][sk]     = *(const f16x8*)(Bp + k0);
            *(f16x8*)&Bs[sm][sk + 8] = *(const f16x8*)(Bp + k0 + 8);
            __syncthreads();
            f16x8 af[4], bf[4];
#pragma unroll
            for (int i = 0; i < 4; i++) af[i] = *(const f16x8*)&As[wr * 64 + i * 16 + fr][kk];
#pragma unroll
            for (int i = 0; i < 4; i++) bf[i] = *(const f16x8*)&Bs[wc * 64 + i * 16 + fr][kk];
#pragma unroll
            for (int i = 0; i < 4; i++)
#pragma unroll
                for (int j = 0; j < 4; j++)
                    acc[i][j] = __builtin_amdgcn_mfma_f32_16x16x32_f16(af[i], bf[j], acc[i][j], 0, 0, 0);
        }
    }

    const int rl = (lane >> 4) * 4, cl = lane & 15;
#pragma unroll
    for (int i = 0; i < 4; i++) {
#pragma unroll
        for (int j = 0; j < 4; j++) {
            int cc = n0 + wc * 64 + j * 16 + cl;
            float bv = bias[cc];
#pragma unroll
            for (int q = 0; q < 4; q++) {
                int rr = m0 + wr * 64 + i * 16 + rl + q;
                float v = acc[i][j][q] + bv;
                size_t o = (size_t)rr * Nc + cc;
                if (EPI == 1) {
                    float ge = gelu_exact(v);
                    half_t h = (half_t)ge;
                    Ch[o] = h;
                    Cl[o] = (half_t)(ge - (float)h);
                } else {
                    Cf[o] = v;
                }
            }
        }
    }
}

// ---------------- router: logits, softmax, top2, gates, expert lists ----------------
__global__ __launch_bounds__(256) void router_kernel(
    const float* __restrict__ x3, const float* __restrict__ wrm,
    int* __restrict__ cnt, int* __restrict__ aid, float* __restrict__ gate)
{
    __shared__ float wl[NEXP][DIM];
    const int tid = threadIdx.x;
    for (int i = tid; i < NEXP * DIM / 4; i += 256)
        reinterpret_cast<float4*>(&wl[0][0])[i] = reinterpret_cast<const float4*>(wrm)[i];
    __syncthreads();
    const int w = tid >> 6, lane = tid & 63;
    const int token = blockIdx.x * 4 + w;
    const float* xr = x3 + (size_t)token * DIM;
    float a[NEXP];
#pragma unroll
    for (int e = 0; e < NEXP; e++) a[e] = 0.f;
    for (int d = lane; d < DIM; d += 64) {
        float xv = xr[d];
#pragma unroll
        for (int e = 0; e < NEXP; e++) a[e] += xv * wl[e][d];
    }
#pragma unroll
    for (int e = 0; e < NEXP; e++)
#pragma unroll
        for (int off = 32; off; off >>= 1) a[e] += __shfl_xor(a[e], off);
    if (lane == 0) {
        float m = a[0];
#pragma unroll
        for (int e = 1; e < NEXP; e++) m = fmaxf(m, a[e]);
        float p[NEXP], s = 0.f;
#pragma unroll
        for (int e = 0; e < NEXP; e++) { p[e] = expf(a[e] - m); s += p[e]; }
        float inv = 1.f / s;
#pragma unroll
        for (int e = 0; e < NEXP; e++) p[e] *= inv;
        int i1 = 0; float v1 = p[0];
#pragma unroll
        for (int e = 1; e < NEXP; e++) if (p[e] > v1) { v1 = p[e]; i1 = e; }
        int i2 = -1; float v2 = -1.f;
#pragma unroll
        for (int e = 0; e < NEXP; e++) if (e != i1 && p[e] > v2) { v2 = p[e]; i2 = e; }
        float den = v1 + v2;
        int s1 = atomicAdd(&cnt[i1], 1);
        int s2 = atomicAdd(&cnt[i2], 1);
        aid[i1 * NTOK + s1] = token * 2;
        aid[i2 * NTOK + s2] = token * 2 + 1;
        gate[token * 2]     = v1 / den;
        gate[token * 2 + 1] = v2 / den;
    }
}

// ---------------- expert GEMM1: He[a] = gelu(x3[tok] @ ew1[e] + eb1[e]) ----------------
__global__ __launch_bounds__(256) void egemm1_kernel(
    const half_t* __restrict__ X,   // [NTOK][DIM]
    const half_t* __restrict__ W,   // [E][EHID][DIM]  (transposed)
    const float* __restrict__ eb1,  // [E][EHID]
    const int* __restrict__ cnt, const int* __restrict__ aid,
    half_t* __restrict__ He)        // [2*NTOK][EHID]
{
    const int bid = blockIdx.x;
    const int e = bid >> 9, rem = bid & 511;
    const int mt = rem >> 3, nt = rem & 7;
    const int ne = cnt[e];
    if (mt * 128 >= ne) return;
    __shared__ half_t As[128][40];
    __shared__ half_t Bs[128][40];
    __shared__ int rowmap[128];
    const int tid = threadIdx.x;
    if (tid < 128) {
        int slot = mt * 128 + tid;
        rowmap[tid] = (slot < ne) ? aid[e * NTOK + slot] : -1;
    }
    __syncthreads();
    const int lane = tid & 63, wid = tid >> 6;
    const int wr = wid >> 1, wc = wid & 1;
    const int sm = tid >> 1, sk = (tid & 1) * 16;
    const int arow = rowmap[sm];
    const half_t* Ap = (arow >= 0) ? X + (size_t)(arow >> 1) * DIM + sk : (const half_t*)0;
    const half_t* Bp = W + (size_t)e * EHID * DIM + (size_t)(nt * 128 + sm) * DIM + sk;
    f32x4 acc[4][4];
#pragma unroll
    for (int i = 0; i < 4; i++)
#pragma unroll
        for (int j = 0; j < 4; j++)
#pragma unroll
            for (int q = 0; q < 4; q++) acc[i][j][q] = 0.f;
    const int kk = (lane >> 4) * 8, fr = lane & 15;
    const f16x8 zz = f16x8_zero();
#pragma unroll 1
    for (int k0 = 0; k0 < DIM; k0 += 32) {
        __syncthreads();
        if (Ap) {
            *(f16x8*)&As[sm][sk]     = *(const f16x8*)(Ap + k0);
            *(f16x8*)&As[sm][sk + 8] = *(const f16x8*)(Ap + k0 + 8);
        } else {
            *(f16x8*)&As[sm][sk]     = zz;
            *(f16x8*)&As[sm][sk + 8] = zz;
        }
        *(f16x8*)&Bs[sm][sk]     = *(const f16x8*)(Bp + k0);
        *(f16x8*)&Bs[sm][sk + 8] = *(const f16x8*)(Bp + k0 + 8);
        __syncthreads();
        f16x8 af[4], bf[4];
#pragma unroll
        for (int i = 0; i < 4; i++) af[i] = *(const f16x8*)&As[wr * 64 + i * 16 + fr][kk];
#pragma unroll
        for (int i = 0; i < 4; i++) bf[i] = *(const f16x8*)&Bs[wc * 64 + i * 16 + fr][kk];
#pragma unroll
        for (int i = 0; i < 4; i++)
#pragma unroll
            for (int j = 0; j < 4; j++)
                acc[i][j] = __builtin_amdgcn_mfma_f32_16x16x32_f16(af[i], bf[j], acc[i][j], 0, 0, 0);
    }
    const int rl = (lane >> 4) * 4, cl = lane & 15;
#pragma unroll
    for (int i = 0; i < 4; i++)
#pragma unroll
        for (int q = 0; q < 4; q++) {
            int r = wr * 64 + i * 16 + rl + q;
            int a = rowmap[r];
            if (a >= 0) {
#pragma unroll
                for (int j = 0; j < 4; j++) {
                    int cc = nt * 128 + wc * 64 + j * 16 + cl;
                    float v = acc[i][j][q] + eb1[e * EHID + cc];
                    He[(size_t)a * EHID + cc] = (half_t)gelu_exact(v);
                }
            }
        }
}

// ---------------- expert GEMM2: Ye[a] = (He[a] @ ew2[e] + eb2[e]) * gate[a] ----------------
__global__ __launch_bounds__(256) void egemm2_kernel(
    const half_t* __restrict__ Hin,  // [2*NTOK][EHID]
    const half_t* __restrict__ W,    // [E][DIM][EHID]  (transposed)
    const float* __restrict__ eb2,   // [E][DIM]
    const int* __restrict__ cnt, const int* __restrict__ aid,
    const float* __restrict__ gate,
    float* __restrict__ Ye)          // [2*NTOK][DIM]
{
    const int bid = blockIdx.x;
    const int e = bid >> 8, rem = bid & 255;
    const int mt = rem >> 2, nt = rem & 3;
    const int ne = cnt[e];
    if (mt * 128 >= ne) return;
    __shared__ half_t As[128][40];
    __shared__ half_t Bs[128][40];
    __shared__ int rowmap[128];
    const int tid = threadIdx.x;
    if (tid < 128) {
        int slot = mt * 128 + tid;
        rowmap[tid] = (slot < ne) ? aid[e * NTOK + slot] : -1;
    }
    __syncthreads();
    const int lane = tid & 63, wid = tid >> 6;
    const int wr = wid >> 1, wc = wid & 1;
    const int sm = tid >> 1, sk = (tid & 1) * 16;
    const int arow = rowmap[sm];
    const half_t* Ap = (arow >= 0) ? Hin + (size_t)arow * EHID + sk : (const half_t*)0;
    const half_t* Bp = W + (size_t)e * DIM * EHID + (size_t)(nt * 128 + sm) * EHID + sk;
    f32x4 acc[4][4];
#pragma unroll
    for (int i = 0; i < 4; i++)
#pragma unroll
        for (int j = 0; j < 4; j++)
#pragma unroll
            for (int q = 0; q < 4; q++) acc[i][j][q] = 0.f;
    const int kk = (lane >> 4) * 8, fr = lane & 15;
    const f16x8 zz = f16x8_zero();
#pragma unroll 1
    for (int k0 = 0; k0 < EHID; k0 += 32) {
        __syncthreads();
        if (Ap) {
            *(f16x8*)&As[sm][sk]     = *(const f16x8*)(Ap + k0);
            *(f16x8*)&As[sm][sk + 8] = *(const f16x8*)(Ap + k0 + 8);
        } else {
            *(f16x8*)&As[sm][sk]     = zz;
            *(f16x8*)&As[sm][sk + 8] = zz;
        }
        *(f16x8*)&Bs[sm][sk]     = *(const f16x8*)(Bp + k0);
        *(f16x8*)&Bs[sm][sk + 8] = *(const f16x8*)(Bp + k0 + 8);
        __syncthreads();
        f16x8 af[4], bf[4];
#pragma unroll
        for (int i = 0; i < 4; i++) af[i] = *(const f16x8*)&As[wr * 64 + i * 16 + fr][kk];
#pragma unroll
        for (int i = 0; i < 4; i++) bf[i] = *(const f16x8*)&Bs[wc * 64 + i * 16 + fr][kk];
#pragma unroll
        for (int i = 0; i < 4; i++)
#pragma unroll
            for (int j = 0; j < 4; j++)
                acc[i][j] = __builtin_amdgcn_mfma_f32_16x16x32_f16(af[i], bf[j], acc[i][j], 0, 0, 0);
    }
    const int rl = (lane >> 4) * 4, cl = lane & 15;
#pragma unroll
    for (int i = 0; i < 4; i++)
#pragma unroll
        for (int q = 0; q < 4; q++) {
            int r = wr * 64 + i * 16 + rl + q;
            int a = rowmap[r];
            if (a >= 0) {
                float gv = gate[a];
#pragma unroll
                for (int j = 0; j < 4; j++) {
                    int cc = nt * 128 + wc * 64 + j * 16 + cl;
                    float v = (acc[i][j][q] + eb2[e * DIM + cc]) * gv;
                    Ye[(size_t)a * DIM + cc] = v;
                }
            }
        }
}

// ---------------- combine two expert outputs per token + final LN ----------------
__global__ __launch_bounds__(256) void combine_lnf_kernel(
    const float* __restrict__ Ye, const float* __restrict__ g, const float* __restrict__ b,
    float* __restrict__ out)
{
    const int t = blockIdx.x, tid = threadIdx.x;
    __shared__ float red[4];
    float2 y0 = reinterpret_cast<const float2*>(Ye + (size_t)(2 * t) * DIM)[tid];
    float2 y1 = reinterpret_cast<const float2*>(Ye + (size_t)(2 * t + 1) * DIM)[tid];
    float z0 = y0.x + y1.x, z1 = y0.y + y1.y;
    float mean = block_sum4(z0 + z1, red, tid) * (1.0f / DIM);
    float d0 = z0 - mean, d1 = z1 - mean;
    float var = block_sum4(d0 * d0 + d1 * d1, red, tid) * (1.0f / DIM);
    float rstd = rsqrtf(var + 1e-5f);
    int d = tid * 2;
    out[(size_t)t * DIM + d]     = d0 * rstd * g[d]     + b[d];
    out[(size_t)t * DIM + d + 1] = d1 * rstd * g[d + 1] + b[d + 1];
    if (t == 0 && tid == 0) out[(size_t)NTOK * DIM] = 0.f;  // aux_loss
}

__global__ void zero_cnt_kernel(int* cnt) {
    if (threadIdx.x < NEXP) cnt[threadIdx.x] = 0;
}

extern "C" void kernel_launch(void* const* d_in, const int* in_sizes, int n_in,
                              void* d_out, int out_size, void* d_ws, size_t ws_size,
                              hipStream_t stream)
{
    (void)in_sizes; (void)n_in; (void)out_size; (void)ws_size;
    const float* x    = (const float*)d_in[0];
    const float* ln1g = (const float*)d_in[1];
    const float* ln1b = (const float*)d_in[2];
    const float* w1   = (const float*)d_in[3];
    const float* b1   = (const float*)d_in[4];
    const float* w2   = (const float*)d_in[5];
    const float* b2   = (const float*)d_in[6];
    const float* ln2g = (const float*)d_in[7];
    const float* ln2b = (const float*)d_in[8];
    const float* wrm  = (const float*)d_in[9];
    const float* ew1  = (const float*)d_in[10];
    const float* eb1  = (const float*)d_in[11];
    const float* ew2  = (const float*)d_in[12];
    const float* eb2  = (const float*)d_in[13];
    const float* lnfg = (const float*)d_in[14];
    const float* lnfb = (const float*)d_in[15];
    float* out = (float*)d_out;

    char* w = (char*)d_ws;
    size_t off = 0;
    auto take = [&](size_t bytes) {
        char* p = w + off;
        off += bytes;
        off = (off + 255) & ~(size_t)255;
        return p;
    };
    half_t* xh_h  = (half_t*)take((size_t)NTOK * DIM * 2);
    half_t* xh_l  = (half_t*)take((size_t)NTOK * DIM * 2);
    half_t* w1t_h = (half_t*)take((size_t)DIM * MHID * 2);
    half_t* w1t_l = (half_t*)take((size_t)DIM * MHID * 2);
    half_t* w2t_h = (half_t*)take((size_t)MHID * DIM * 2);
    half_t* w2t_l = (half_t*)take((size_t)MHID * DIM * 2);
    char*   big   = take((size_t)NTOK * MHID * 2 * 2);        // 64 MiB: a1 hi/lo, later He + Ye
    half_t* a1h   = (half_t*)big;
    half_t* a1l   = (half_t*)(big + (size_t)NTOK * MHID * 2);
    half_t* heh   = (half_t*)big;                              // alias (a1 dead after gemm2)
    float*  yef   = (float*)(big + (size_t)NTOK * MHID * 2);   // alias
    float*  x3f   = (float*)take((size_t)NTOK * DIM * 4);      // h buffer, then x3 f32
    half_t* x3h   = (half_t*)take((size_t)NTOK * DIM * 2);
    half_t* ew1t  = (half_t*)take((size_t)NEXP * DIM * EHID * 2);
    half_t* ew2t  = (half_t*)take((size_t)NEXP * EHID * DIM * 2);
    int*    cnt   = (int*)take(256);
    int*    aid   = (int*)take((size_t)NEXP * NTOK * 4);
    float*  gate  = (float*)take((size_t)NTOK * 2 * 4);

    zero_cnt_kernel<<<1, 64, 0, stream>>>(cnt);
    ln1_split_kernel<<<NTOK, 256, 0, stream>>>(x, ln1g, ln1b, xh_h, xh_l);
    transpose_split_kernel<<<dim3(MHID / 32, DIM / 32, 1), dim3(32, 8), 0, stream>>>(w1, w1t_h, w1t_l, DIM, MHID);
    transpose_split_kernel<<<dim3(DIM / 32, MHID / 32, 1), dim3(32, 8), 0, stream>>>(w2, w2t_h, w2t_l, MHID, DIM);
    transpose_split_kernel<<<dim3(EHID / 32, DIM / 32, NEXP), dim3(32, 8), 0, stream>>>(ew1, ew1t, (half_t*)0, DIM, EHID);
    transpose_split_kernel<<<dim3(DIM / 32, EHID / 32, NEXP), dim3(32, 8), 0, stream>>>(ew2, ew2t, (half_t*)0, EHID, DIM);
    gemm3_kernel<1><<<dim3(NTOK / 128, MHID / 128), 256, 0, stream>>>(
        xh_h, xh_l, w1t_h, w1t_l, b1, (float*)0, a1h, a1l, NTOK, MHID, DIM);
    gemm3_kernel<0><<<dim3(NTOK / 128, DIM / 128), 256, 0, stream>>>(
        a1h, a1l, w2t_h, w2t_l, b2, x3f, (half_t*)0, (half_t*)0, NTOK, DIM, MHID);
    resid_ln2_kernel<<<NTOK, 256, 0, stream>>>(x, x3f, ln2g, ln2b, x3h);
    router_kernel<<<NTOK / 4, 256, 0, stream>>>(x3f, wrm, cnt, aid, gate);
    egemm1_kernel<<<NEXP * (NTOK / 128) * (EHID / 128), 256, 0, stream>>>(x3h, ew1t, eb1, cnt, aid, heh);
    egemm2_kernel<<<NEXP * (NTOK / 128) * (DIM / 128), 256, 0, stream>>>(heh, ew2t, eb2, cnt, aid, gate, yef);
    combine_lnf_kernel<<<NTOK, 256, 0, stream>>>(yef, lnfg, lnfb, out);
}

// Round 2
// 594.617 us; speedup vs baseline: 1.0003x; 1.0003x over previous
//
#include <hip/hip_runtime.h>

#define NTOK 8192
#define DIM  512
#define MHID 2048
#define EHID 1024
#define NEXP 8

using half_t = _Float16;
typedef _Float16 f16x8 __attribute__((ext_vector_type(8)));
typedef float    f32x4 __attribute__((ext_vector_type(4)));

__device__ __forceinline__ float gelu_exact(float v) {
    return 0.5f * v * (1.0f + erff(v * 0.70710678118654752f));
}

__device__ __forceinline__ f16x8 f16x8_zero() {
    f16x8 v;
#pragma unroll
    for (int i = 0; i < 8; i++) v[i] = (_Float16)0.f;
    return v;
}

// all-threads-return block sum over 4 waves (256 threads)
__device__ __forceinline__ float block_sum4(float v, float* red, int tid) {
#pragma unroll
    for (int off = 32; off; off >>= 1) v += __shfl_down(v, off);
    if ((tid & 63) == 0) red[tid >> 6] = v;
    __syncthreads();
    float r = red[0] + red[1] + red[2] + red[3];
    __syncthreads();
    return r;
}

// ---------------- LN1 + fp16 hi/lo split ----------------
__global__ __launch_bounds__(256) void ln1_split_kernel(
    const float* __restrict__ x, const float* __restrict__ g, const float* __restrict__ b,
    half_t* __restrict__ xh, half_t* __restrict__ xl)
{
    const int row = blockIdx.x, tid = threadIdx.x;
    __shared__ float red[4];
    const size_t base = (size_t)row * DIM;
    float2 v = reinterpret_cast<const float2*>(x + base)[tid];
    float mean = block_sum4(v.x + v.y, red, tid) * (1.0f / DIM);
    float d0 = v.x - mean, d1 = v.y - mean;
    float var = block_sum4(d0 * d0 + d1 * d1, red, tid) * (1.0f / DIM);
    float rstd = rsqrtf(var + 1e-5f);
    int d = tid * 2;
    float y0 = d0 * rstd * g[d]     + b[d];
    float y1 = d1 * rstd * g[d + 1] + b[d + 1];
    half_t h0 = (half_t)y0, h1 = (half_t)y1;
    xh[base + d] = h0;  xh[base + d + 1] = h1;
    xl[base + d]     = (half_t)(y0 - (float)h0);
    xl[base + d + 1] = (half_t)(y1 - (float)h1);
}

// ---------------- x2 = x + h ; x3 = LN2(x2) + x2 (in place over h) ----------------
__global__ __launch_bounds__(256) void resid_ln2_kernel(
    const float* __restrict__ x, float* __restrict__ hio,
    const float* __restrict__ g, const float* __restrict__ b,
    half_t* __restrict__ x3h)
{
    const int row = blockIdx.x, tid = threadIdx.x;
    __shared__ float red[4];
    const size_t base = (size_t)row * DIM;
    float2 xv = reinterpret_cast<const float2*>(x + base)[tid];
    float2 hv = reinterpret_cast<float2*>(hio + base)[tid];
    float z0 = xv.x + hv.x, z1 = xv.y + hv.y;
    float mean = block_sum4(z0 + z1, red, tid) * (1.0f / DIM);
    float d0 = z0 - mean, d1 = z1 - mean;
    float var = block_sum4(d0 * d0 + d1 * d1, red, tid) * (1.0f / DIM);
    float rstd = rsqrtf(var + 1e-5f);
    int d = tid * 2;
    float y0 = d0 * rstd * g[d]     + b[d]     + z0;
    float y1 = d1 * rstd * g[d + 1] + b[d + 1] + z1;
    float2 o; o.x = y0; o.y = y1;
    reinterpret_cast<float2*>(hio + base)[tid] = o;
    x3h[base + d]     = (half_t)y0;
    x3h[base + d + 1] = (half_t)y1;
}

// ---------------- transpose [R][C] -> [C][R], cast to f16 (optional lo split) ----------------
__global__ void transpose_split_kernel(const float* __restrict__ in,
                                       half_t* __restrict__ oh, half_t* __restrict__ ol,
                                       int R, int C)
{
    __shared__ float t[32][33];
    const size_t mo = (size_t)blockIdx.z * (size_t)R * (size_t)C;
    const int c0 = blockIdx.x * 32, r0 = blockIdx.y * 32;
    const int tx = threadIdx.x, ty = threadIdx.y;
    for (int i = ty; i < 32; i += 8) t[i][tx] = in[mo + (size_t)(r0 + i) * C + c0 + tx];
    __syncthreads();
    for (int i = ty; i < 32; i += 8) {
        float v = t[tx][i];
        size_t o = mo + (size_t)(c0 + i) * R + r0 + tx;
        half_t h = (half_t)v;
        oh[o] = h;
        if (ol) ol[o] = (half_t)(v - (float)h);
    }
}

// ---------------- split-3 f16 MFMA GEMM: C = (Ah+Al)(Bh+Bl)^T approx ----------------
// A: [M][K] f16 hi/lo.  B: [Nc][K] f16 hi/lo (pre-transposed weights).
// EPI==1: gelu(acc+bias) -> split f16 hi/lo outs.  EPI==0: acc+bias -> f32 out.
template <int EPI>
__global__ __launch_bounds__(256) void gemm3_kernel(
    const half_t* __restrict__ A0, const half_t* __restrict__ A1,
    const half_t* __restrict__ B0, const half_t* __restrict__ B1,
    const float* __restrict__ bias,
    float* __restrict__ Cf, half_t* __restrict__ Ch, half_t* __restrict__ Cl,
    int M, int Nc, int K)
{
    __shared__ half_t As[128][40];
    __shared__ half_t Bs[128][40];
    const int m0 = blockIdx.x * 128, n0 = blockIdx.y * 128;
    const int tid = threadIdx.x;
    const int lane = tid & 63, wid = tid >> 6;
    const int wr = wid >> 1, wc = wid & 1;
    f32x4 acc[4][4];
#pragma unroll
    for (int i = 0; i < 4; i++)
#pragma unroll
        for (int j = 0; j < 4; j++)
#pragma unroll
            for (int q = 0; q < 4; q++) acc[i][j][q] = 0.f;

    const int sm = tid >> 1, sk = (tid & 1) * 16;
    const size_t aoff = (size_t)(m0 + sm) * K + sk;
    const size_t boff = (size_t)(n0 + sm) * K + sk;
    const int kk = (lane >> 4) * 8;
    const int fr = lane & 15;

#pragma unroll 1
    for (int term = 0; term < 3; ++term) {
        const half_t* Ap = (term == 1 ? A1 : A0) + aoff;
        const half_t* Bp = (term == 2 ? B1 : B0) + boff;
#pragma unroll 1
        for (int k0 = 0; k0 < K; k0 += 32) {
            __syncthreads();
            *(f16x8*)&As[sm][sk]     = *(const f16x8*)(Ap + k0);
            *(f16x8*)&As[sm][sk + 8] = *(const f16x8*)(Ap + k0 + 8);
            *(f16x8*)&Bs[sm][sk]     = *(const f16x8*)(Bp + k0);
            *(f16x8*)&Bs[sm][sk + 8] = *(const f16x8*)(Bp + k0 + 8);
            __syncthreads();
            f16x8 af[4], bf[4];
#pragma unroll
            for (int i = 0; i < 4; i++) af[i] = *(const f16x8*)&As[wr * 64 + i * 16 + fr][kk];
#pragma unroll
            for (int i = 0; i < 4; i++) bf[i] = *(const f16x8*)&Bs[wc * 64 + i * 16 + fr][kk];
#pragma unroll
            for (int i = 0; i < 4; i++)
#pragma unroll
                for (int j = 0; j < 4; j++)
                    acc[i][j] = __builtin_amdgcn_mfma_f32_16x16x32_f16(af[i], bf[j], acc[i][j], 0, 0, 0);
        }
    }

    const int rl = (lane >> 4) * 4, cl = lane & 15;
#pragma unroll
    for (int i = 0; i < 4; i++) {
#pragma unroll
        for (int j = 0; j < 4; j++) {
            int cc = n0 + wc * 64 + j * 16 + cl;
            float bv = bias[cc];
#pragma unroll
            for (int q = 0; q < 4; q++) {
                int rr = m0 + wr * 64 + i * 16 + rl + q;
                float v = acc[i][j][q] + bv;
                size_t o = (size_t)rr * Nc + cc;
                if (EPI == 1) {
                    float ge = gelu_exact(v);
                    half_t h = (half_t)ge;
                    Ch[o] = h;
                    Cl[o] = (half_t)(ge - (float)h);
                } else {
                    Cf[o] = v;
                }
            }
        }
    }
}

// ---------------- router: logits, softmax, top2, gates, expert lists ----------------
__global__ __launch_bounds__(256) void router_kernel(
    const float* __restrict__ x3, const float* __restrict__ wrm,
    int* __restrict__ cnt, int* __restrict__ aid, float* __restrict__ gate)
{
    __shared__ float wl[NEXP][DIM];
    const int tid = threadIdx.x;
    for (int i = tid; i < NEXP * DIM / 4; i += 256)
        reinterpret_cast<float4*>(&wl[0][0])[i] = reinterpret_cast<const float4*>(wrm)[i];
    __syncthreads();
    const int w = tid >> 6, lane = tid & 63;
    const int token = blockIdx.x * 4 + w;
    const float* xr = x3 + (size_t)token * DIM;
    float a[NEXP];
#pragma unroll
    for (int e = 0; e < NEXP; e++) a[e] = 0.f;
    for (int d = lane; d < DIM; d += 64) {
        float xv = xr[d];
#pragma unroll
        for (int e = 0; e < NEXP; e++) a[e] += xv * wl[e][d];
    }
#pragma unroll
    for (int e = 0; e < NEXP; e++)
#pragma unroll
        for (int off = 32; off; off >>= 1) a[e] += __shfl_xor(a[e], off);
    if (lane == 0) {
        float m = a[0];
#pragma unroll
        for (int e = 1; e < NEXP; e++) m = fmaxf(m, a[e]);
        float p[NEXP], s = 0.f;
#pragma unroll
        for (int e = 0; e < NEXP; e++) { p[e] = expf(a[e] - m); s += p[e]; }
        float inv = 1.f / s;
#pragma unroll
        for (int e = 0; e < NEXP; e++) p[e] *= inv;
        int i1 = 0; float v1 = p[0];
#pragma unroll
        for (int e = 1; e < NEXP; e++) if (p[e] > v1) { v1 = p[e]; i1 = e; }
        int i2 = -1; float v2 = -1.f;
#pragma unroll
        for (int e = 0; e < NEXP; e++) if (e != i1 && p[e] > v2) { v2 = p[e]; i2 = e; }
        float den = v1 + v2;
        int s1 = atomicAdd(&cnt[i1], 1);
        int s2 = atomicAdd(&cnt[i2], 1);
        aid[i1 * NTOK + s1] = token * 2;
        aid[i2 * NTOK + s2] = token * 2 + 1;
        gate[token * 2]     = v1 / den;
        gate[token * 2 + 1] = v2 / den;
    }
}

// ---------------- expert GEMM1: He[a] = gelu(x3[tok] @ ew1[e] + eb1[e]) ----------------
__global__ __launch_bounds__(256) void egemm1_kernel(
    const half_t* __restrict__ X,   // [NTOK][DIM]
    const half_t* __restrict__ W,   // [E][EHID][DIM]  (transposed)
    const float* __restrict__ eb1,  // [E][EHID]
    const int* __restrict__ cnt, const int* __restrict__ aid,
    half_t* __restrict__ He)        // [2*NTOK][EHID]
{
    const int bid = blockIdx.x;
    const int e = bid >> 9, rem = bid & 511;
    const int mt = rem >> 3, nt = rem & 7;
    const int ne = cnt[e];
    if (mt * 128 >= ne) return;
    __shared__ half_t As[128][40];
    __shared__ half_t Bs[128][40];
    __shared__ int rowmap[128];
    const int tid = threadIdx.x;
    if (tid < 128) {
        int slot = mt * 128 + tid;
        rowmap[tid] = (slot < ne) ? aid[e * NTOK + slot] : -1;
    }
    __syncthreads();
    const int lane = tid & 63, wid = tid >> 6;
    const int wr = wid >> 1, wc = wid & 1;
    const int sm = tid >> 1, sk = (tid & 1) * 16;
    const int arow = rowmap[sm];
    const half_t* Ap = (arow >= 0) ? X + (size_t)(arow >> 1) * DIM + sk : (const half_t*)0;
    const half_t* Bp = W + (size_t)e * EHID * DIM + (size_t)(nt * 128 + sm) * DIM + sk;
    f32x4 acc[4][4];
#pragma unroll
    for (int i = 0; i < 4; i++)
#pragma unroll
        for (int j = 0; j < 4; j++)
#pragma unroll
            for (int q = 0; q < 4; q++) acc[i][j][q] = 0.f;
    const int kk = (lane >> 4) * 8, fr = lane & 15;
    const f16x8 zz = f16x8_zero();
#pragma unroll 1
    for (int k0 = 0; k0 < DIM; k0 += 32) {
        __syncthreads();
        if (Ap) {
            *(f16x8*)&As[sm][sk]     = *(const f16x8*)(Ap + k0);
            *(f16x8*)&As[sm][sk + 8] = *(const f16x8*)(Ap + k0 + 8);
        } else {
            *(f16x8*)&As[sm][sk]     = zz;
            *(f16x8*)&As[sm][sk + 8] = zz;
        }
        *(f16x8*)&Bs[sm][sk]     = *(const f16x8*)(Bp + k0);
        *(f16x8*)&Bs[sm][sk + 8] = *(const f16x8*)(Bp + k0 + 8);
        __syncthreads();
        f16x8 af[4], bf[4];
#pragma unroll
        for (int i = 0; i < 4; i++) af[i] = *(const f16x8*)&As[wr * 64 + i * 16 + fr][kk];
#pragma unroll
        for (int i = 0; i < 4; i++) bf[i] = *(const f16x8*)&Bs[wc * 64 + i * 16 + fr][kk];
#pragma unroll
        for (int i = 0; i < 4; i++)
#pragma unroll
            for (int j = 0; j < 4; j++)
                acc[i][j] = __builtin_amdgcn_mfma_f32_16x16x32_f16(af[i], bf[j], acc[i][j], 0, 0, 0);
    }
    const int rl = (lane >> 4) * 4, cl = lane & 15;
#pragma unroll
    for (int i = 0; i < 4; i++)
#pragma unroll
        for (int q = 0; q < 4; q++) {
            int r = wr * 64 + i * 16 + rl + q;
            int a = rowmap[r];
            if (a >= 0) {
#pragma unroll
                for (int j = 0; j < 4; j++) {
                    int cc = nt * 128 + wc * 64 + j * 16 + cl;
                    float v = acc[i][j][q] + eb1[e * EHID + cc];
                    He[(size_t)a * EHID + cc] = (half_t)gelu_exact(v);
                }
            }
        }
}

// ---------------- expert GEMM2: Ye[a] = (He[a] @ ew2[e] + eb2[e]) * gate[a] ----------------
__global__ __launch_bounds__(256) void egemm2_kernel(
    const half_t* __restrict__ Hin,  // [2*NTOK][EHID]
    const half_t* __restrict__ W,    // [E][DIM][EHID]  (transposed)
    const float* __restrict__ eb2,   // [E][DIM]
    const int* __restrict__ cnt, const int* __restrict__ aid,
    const float* __restrict__ gate,
    float* __restrict__ Ye)          // [2*NTOK][DIM]
{
    const int bid = blockIdx.x;
    const int e = bid >> 8, rem = bid & 255;
    const int mt = rem >> 2, nt = rem & 3;
    const int ne = cnt[e];
    if (mt * 128 >= ne) return;
    __shared__ half_t As[128][40];
    __shared__ half_t Bs[128][40];
    __shared__ int rowmap[128];
    const int tid = threadIdx.x;
    if (tid < 128) {
        int slot = mt * 128 + tid;
        rowmap[tid] = (slot < ne) ? aid[e * NTOK + slot] : -1;
    }
    __syncthreads();
    const int lane = tid & 63, wid = tid >> 6;
    const int wr = wid >> 1, wc = wid & 1;
    const int sm = tid >> 1, sk = (tid & 1) * 16;
    const int arow = rowmap[sm];
    const half_t* Ap = (arow >= 0) ? Hin + (size_t)arow * EHID + sk : (const half_t*)0;
    const half_t* Bp = W + (size_t)e * DIM * EHID + (size_t)(nt * 128 + sm) * EHID + sk;
    f32x4 acc[4][4];
#pragma unroll
    for (int i = 0; i < 4; i++)
#pragma unroll
        for (int j = 0; j < 4; j++)
#pragma unroll
            for (int q = 0; q < 4; q++) acc[i][j][q] = 0.f;
    const int kk = (lane >> 4) * 8, fr = lane & 15;
    const f16x8 zz = f16x8_zero();
#pragma unroll 1
    for (int k0 = 0; k0 < EHID; k0 += 32) {
        __syncthreads();
        if (Ap) {
            *(f16x8*)&As[sm][sk]     = *(const f16x8*)(Ap + k0);
            *(f16x8*)&As[sm][sk + 8] = *(const f16x8*)(Ap + k0 + 8);
        } else {
            *(f16x8*)&As[sm][sk]     = zz;
            *(f16x8*)&As[sm][sk + 8] = zz;
        }
        *(f16x8*)&Bs[sm][sk]     = *(const f16x8*)(Bp + k0);
        *(f16x8*)&Bs[sm][sk + 8] = *(const f16x8*)(Bp + k0 + 8);
        __syncthreads();
        f16x8 af[4], bf[4];
#pragma unroll
        for (int i = 0; i < 4; i++) af[i] = *(const f16x8*)&As[wr * 64 + i * 16 + fr][kk];
#pragma unroll
        for (int i = 0; i < 4; i++) bf[i] = *(const f16x8*)&Bs[wc * 64 + i * 16 + fr][kk];
#pragma unroll
        for (int i = 0; i < 4; i++)
#pragma unroll
            for (int j = 0; j < 4; j++)
                acc[i][j] = __builtin_amdgcn_mfma_f32_16x16x32_f16(af[i], bf[j], acc[i][j], 0, 0, 0);
    }
    const int rl = (lane >> 4) * 4, cl = lane & 15;
#pragma unroll
    for (int i = 0; i < 4; i++)
#pragma unroll
        for (int q = 0; q < 4; q++) {
            int r = wr * 64 + i * 16 + rl + q;
            int a = rowmap[r];
            if (a >= 0) {
                float gv = gate[a];
#pragma unroll
                for (int j = 0; j < 4; j++) {
                    int cc = nt * 128 + wc * 64 + j * 16 + cl;
                    float v = (acc[i][j][q] + eb2[e * DIM + cc]) * gv;
                    Ye[(size_t)a * DIM + cc] = v;
                }
            }
        }
}

// ---------------- combine two expert outputs per token + final LN ----------------
__global__ __launch_bounds__(256) void combine_lnf_kernel(
    const float* __restrict__ Ye, const float* __restrict__ g, const float* __restrict__ b,
    float* __restrict__ out)
{
    const int t = blockIdx.x, tid = threadIdx.x;
    __shared__ float red[4];
    float2 y0 = reinterpret_cast<const float2*>(Ye + (size_t)(2 * t) * DIM)[tid];
    float2 y1 = reinterpret_cast<const float2*>(Ye + (size_t)(2 * t + 1) * DIM)[tid];
    float z0 = y0.x + y1.x, z1 = y0.y + y1.y;
    float mean = block_sum4(z0 + z1, red, tid) * (1.0f / DIM);
    float d0 = z0 - mean, d1 = z1 - mean;
    float var = block_sum4(d0 * d0 + d1 * d1, red, tid) * (1.0f / DIM);
    float rstd = rsqrtf(var + 1e-5f);
    int d = tid * 2;
    out[(size_t)t * DIM + d]     = d0 * rstd * g[d]     + b[d];
    out[(size_t)t * DIM + d + 1] = d1 * rstd * g[d + 1] + b[d + 1];
    if (t == 0 && tid == 0) out[(size_t)NTOK * DIM] = 0.f;  // aux_loss
}

__global__ void zero_cnt_kernel(int* cnt) {
    if (threadIdx.x < NEXP) cnt[threadIdx.x] = 0;
}

extern "C" void kernel_launch(void* const* d_in, const int* in_sizes, int n_in,
                              void* d_out, int out_size, void* d_ws, size_t ws_size,
                              hipStream_t stream)
{
    (void)in_sizes; (void)n_in; (void)out_size; (void)ws_size;
    const float* x    = (const float*)d_in[0];
    const float* ln1g = (const float*)d_in[1];
    const float* ln1b = (const float*)d_in[2];
    const float* w1   = (const float*)d_in[3];
    const float* b1   = (const float*)d_in[4];
    const float* w2   = (const float*)d_in[5];
    const float* b2   = (const float*)d_in[6];
    const float* ln2g = (const float*)d_in[7];
    const float* ln2b = (const float*)d_in[8];
    const float* wrm  = (const float*)d_in[9];
    const float* ew1  = (const float*)d_in[10];
    const float* eb1  = (const float*)d_in[11];
    const float* ew2  = (const float*)d_in[12];
    const float* eb2  = (const float*)d_in[13];
    const float* lnfg = (const float*)d_in[14];
    const float* lnfb = (const float*)d_in[15];
    float* out = (float*)d_out;

    char* w = (char*)d_ws;
    size_t off = 0;
    auto take = [&](size_t bytes) {
        char* p = w + off;
        off += bytes;
        off = (off + 255) & ~(size_t)255;
        return p;
    };
    half_t* xh_h  = (half_t*)take((size_t)NTOK * DIM * 2);
    half_t* xh_l  = (half_t*)take((size_t)NTOK * DIM * 2);
    half_t* w1t_h = (half_t*)take((size_t)DIM * MHID * 2);
    half_t* w1t_l = (half_t*)take((size_t)DIM * MHID * 2);
    half_t* w2t_h = (half_t*)take((size_t)MHID * DIM * 2);
    half_t* w2t_l = (half_t*)take((size_t)MHID * DIM * 2);
    char*   big   = take((size_t)NTOK * MHID * 2 * 2);        // 64 MiB: a1 hi/lo, later He + Ye
    half_t* a1h   = (half_t*)big;
    half_t* a1l   = (half_t*)(big + (size_t)NTOK * MHID * 2);
    half_t* heh   = (half_t*)big;                              // alias (a1 dead after gemm2)
    float*  yef   = (float*)(big + (size_t)NTOK * MHID * 2);   // alias
    float*  x3f   = (float*)take((size_t)NTOK * DIM * 4);      // h buffer, then x3 f32
    half_t* x3h   = (half_t*)take((size_t)NTOK * DIM * 2);
    half_t* ew1t  = (half_t*)take((size_t)NEXP * DIM * EHID * 2);
    half_t* ew2t  = (half_t*)take((size_t)NEXP * EHID * DIM * 2);
    int*    cnt   = (int*)take(256);
    int*    aid   = (int*)take((size_t)NEXP * NTOK * 4);
    float*  gate  = (float*)take((size_t)NTOK * 2 * 4);

    zero_cnt_kernel<<<1, 64, 0, stream>>>(cnt);
    ln1_split_kernel<<<NTOK, 256, 0, stream>>>(x, ln1g, ln1b, xh_h, xh_l);
    transpose_split_kernel<<<dim3(MHID / 32, DIM / 32, 1), dim3(32, 8), 0, stream>>>(w1, w1t_h, w1t_l, DIM, MHID);
    transpose_split_kernel<<<dim3(DIM / 32, MHID / 32, 1), dim3(32, 8), 0, stream>>>(w2, w2t_h, w2t_l, MHID, DIM);
    transpose_split_kernel<<<dim3(EHID / 32, DIM / 32, NEXP), dim3(32, 8), 0, stream>>>(ew1, ew1t, (half_t*)0, DIM, EHID);
    transpose_split_kernel<<<dim3(DIM / 32, EHID / 32, NEXP), dim3(32, 8), 0, stream>>>(ew2, ew2t, (half_t*)0, EHID, DIM);
    gemm3_kernel<1><<<dim3(NTOK / 128, MHID / 128), 256, 0, stream>>>(
        xh_h, xh_l, w1t_h, w1t_l, b1, (float*)0, a1h, a1l, NTOK, MHID, DIM);
    gemm3_kernel<0><<<dim3(NTOK / 128, DIM / 128), 256, 0, stream>>>(
        a1h, a1l, w2t_h, w2t_l, b2, x3f, (half_t*)0, (half_t*)0, NTOK, DIM, MHID);
    resid_ln2_kernel<<<NTOK, 256, 0, stream>>>(x, x3f, ln2g, ln2b, x3h);
    router_kernel<<<NTOK / 4, 256, 0, stream>>>(x3f, wrm, cnt, aid, gate);
    egemm1_kernel<<<NEXP * (NTOK / 128) * (EHID / 128), 256, 0, stream>>>(x3h, ew1t, eb1, cnt, aid, heh);
    egemm2_kernel<<<NEXP * (NTOK / 128) * (DIM / 128), 256, 0, stream>>>(heh, ew2t, eb2, cnt, aid, gate, yef);
    combine_lnf_kernel<<<NTOK, 256, 0, stream>>>(yef, lnfg, lnfb, out);
}

// Round 3
// 594.203 us; speedup vs baseline: 1.0010x; 1.0007x over previous
//
#include <hip/hip_runtime.h>

#define NTOK 8192
#define DIM  512
#define MHID 2048
#define EHID 1024
#define NEXP 8

using half_t = _Float16;
typedef _Float16 f16x8 __attribute__((ext_vector_type(8)));
typedef float    f32x4 __attribute__((ext_vector_type(4)));

__device__ __forceinline__ float gelu_exact(float v) {
    return 0.5f * v * (1.0f + erff(v * 0.70710678118654752f));
}

__device__ __forceinline__ f16x8 f16x8_zero() {
    f16x8 v;
#pragma unroll
    for (int i = 0; i < 8; i++) v[i] = (_Float16)0.f;
    return v;
}

// all-threads-return block sum over 4 waves (256 threads)
__device__ __forceinline__ float block_sum4(float v, float* red, int tid) {
#pragma unroll
    for (int off = 32; off; off >>= 1) v += __shfl_down(v, off);
    if ((tid & 63) == 0) red[tid >> 6] = v;
    __syncthreads();
    float r = red[0] + red[1] + red[2] + red[3];
    __syncthreads();
    return r;
}

// ---------------- LN1 + fp16 hi/lo split ----------------
__global__ __launch_bounds__(256) void ln1_split_kernel(
    const float* __restrict__ x, const float* __restrict__ g, const float* __restrict__ b,
    half_t* __restrict__ xh, half_t* __restrict__ xl)
{
    const int row = blockIdx.x, tid = threadIdx.x;
    __shared__ float red[4];
    const size_t base = (size_t)row * DIM;
    float2 v = reinterpret_cast<const float2*>(x + base)[tid];
    float mean = block_sum4(v.x + v.y, red, tid) * (1.0f / DIM);
    float d0 = v.x - mean, d1 = v.y - mean;
    float var = block_sum4(d0 * d0 + d1 * d1, red, tid) * (1.0f / DIM);
    float rstd = rsqrtf(var + 1e-5f);
    int d = tid * 2;
    float y0 = d0 * rstd * g[d]     + b[d];
    float y1 = d1 * rstd * g[d + 1] + b[d + 1];
    half_t h0 = (half_t)y0, h1 = (half_t)y1;
    xh[base + d] = h0;  xh[base + d + 1] = h1;
    xl[base + d]     = (half_t)(y0 - (float)h0);
    xl[base + d + 1] = (half_t)(y1 - (float)h1);
}

// ---------------- x2 = x + h ; x3 = LN2(x2) + x2 (in place over h) ----------------
__global__ __launch_bounds__(256) void resid_ln2_kernel(
    const float* __restrict__ x, float* __restrict__ hio,
    const float* __restrict__ g, const float* __restrict__ b,
    half_t* __restrict__ x3h)
{
    const int row = blockIdx.x, tid = threadIdx.x;
    __shared__ float red[4];
    const size_t base = (size_t)row * DIM;
    float2 xv = reinterpret_cast<const float2*>(x + base)[tid];
    float2 hv = reinterpret_cast<float2*>(hio + base)[tid];
    float z0 = xv.x + hv.x, z1 = xv.y + hv.y;
    float mean = block_sum4(z0 + z1, red, tid) * (1.0f / DIM);
    float d0 = z0 - mean, d1 = z1 - mean;
    float var = block_sum4(d0 * d0 + d1 * d1, red, tid) * (1.0f / DIM);
    float rstd = rsqrtf(var + 1e-5f);
    int d = tid * 2;
    float y0 = d0 * rstd * g[d]     + b[d]     + z0;
    float y1 = d1 * rstd * g[d + 1] + b[d + 1] + z1;
    float2 o; o.x = y0; o.y = y1;
    reinterpret_cast<float2*>(hio + base)[tid] = o;
    x3h[base + d]     = (half_t)y0;
    x3h[base + d + 1] = (half_t)y1;
}

// ---------------- transpose [R][C] -> [C][R], cast to f16 (optional lo split) ----------------
__global__ void transpose_split_kernel(const float* __restrict__ in,
                                       half_t* __restrict__ oh, half_t* __restrict__ ol,
                                       int R, int C)
{
    __shared__ float t[32][33];
    const size_t mo = (size_t)blockIdx.z * (size_t)R * (size_t)C;
    const int c0 = blockIdx.x * 32, r0 = blockIdx.y * 32;
    const int tx = threadIdx.x, ty = threadIdx.y;
    for (int i = ty; i < 32; i += 8) t[i][tx] = in[mo + (size_t)(r0 + i) * C + c0 + tx];
    __syncthreads();
    for (int i = ty; i < 32; i += 8) {
        float v = t[tx][i];
        size_t o = mo + (size_t)(c0 + i) * R + r0 + tx;
        half_t h = (half_t)v;
        oh[o] = h;
        if (ol) ol[o] = (half_t)(v - (float)h);
    }
}

// ---------------- split-3 f16 MFMA GEMM: C = (Ah+Al)(Bh+Bl)^T approx ----------------
// A: [M][K] f16 hi/lo.  B: [Nc][K] f16 hi/lo (pre-transposed weights).
// EPI==1: gelu(acc+bias) -> split f16 hi/lo outs.  EPI==0: acc+bias -> f32 out.
template <int EPI>
__global__ __launch_bounds__(256) void gemm3_kernel(
    const half_t* __restrict__ A0, const half_t* __restrict__ A1,
    const half_t* __restrict__ B0, const half_t* __restrict__ B1,
    const float* __restrict__ bias,
    float* __restrict__ Cf, half_t* __restrict__ Ch, half_t* __restrict__ Cl,
    int M, int Nc, int K)
{
    __shared__ half_t As[128][40];
    __shared__ half_t Bs[128][40];
    const int m0 = blockIdx.x * 128, n0 = blockIdx.y * 128;
    const int tid = threadIdx.x;
    const int lane = tid & 63, wid = tid >> 6;
    const int wr = wid >> 1, wc = wid & 1;
    f32x4 acc[4][4];
#pragma unroll
    for (int i = 0; i < 4; i++)
#pragma unroll
        for (int j = 0; j < 4; j++)
#pragma unroll
            for (int q = 0; q < 4; q++) acc[i][j][q] = 0.f;

    const int sm = tid >> 1, sk = (tid & 1) * 16;
    const size_t aoff = (size_t)(m0 + sm) * K + sk;
    const size_t boff = (size_t)(n0 + sm) * K + sk;
    const int kk = (lane >> 4) * 8;
    const int fr = lane & 15;

#pragma unroll 1
    for (int term = 0; term < 3; ++term) {
        const half_t* Ap = (term == 1 ? A1 : A0) + aoff;
        const half_t* Bp = (term == 2 ? B1 : B0) + boff;
#pragma unroll 1
        for (int k0 = 0; k0 < K; k0 += 32) {
            __syncthreads();
            *(f16x8*)&As[sm][sk]     = *(const f16x8*)(Ap + k0);
            *(f16x8*)&As[sm][sk + 8] = *(const f16x8*)(Ap + k0 + 8);
            *(f16x8*)&Bs[sm][sk]     = *(const f16x8*)(Bp + k0);
            *(f16x8*)&Bs[sm][sk + 8] = *(const f16x8*)(Bp + k0 + 8);
            __syncthreads();
            f16x8 af[4], bf[4];
#pragma unroll
            for (int i = 0; i < 4; i++) af[i] = *(const f16x8*)&As[wr * 64 + i * 16 + fr][kk];
#pragma unroll
            for (int i = 0; i < 4; i++) bf[i] = *(const f16x8*)&Bs[wc * 64 + i * 16 + fr][kk];
#pragma unroll
            for (int i = 0; i < 4; i++)
#pragma unroll
                for (int j = 0; j < 4; j++)
                    acc[i][j] = __builtin_amdgcn_mfma_f32_16x16x32_f16(af[i], bf[j], acc[i][j], 0, 0, 0);
        }
    }

    const int rl = (lane >> 4) * 4, cl = lane & 15;
#pragma unroll
    for (int i = 0; i < 4; i++) {
#pragma unroll
        for (int j = 0; j < 4; j++) {
            int cc = n0 + wc * 64 + j * 16 + cl;
            float bv = bias[cc];
#pragma unroll
            for (int q = 0; q < 4; q++) {
                int rr = m0 + wr * 64 + i * 16 + rl + q;
                float v = acc[i][j][q] + bv;
                size_t o = (size_t)rr * Nc + cc;
                if (EPI == 1) {
                    float ge = gelu_exact(v);
                    half_t h = (half_t)ge;
                    Ch[o] = h;
                    Cl[o] = (half_t)(ge - (float)h);
                } else {
                    Cf[o] = v;
                }
            }
        }
    }
}

// ---------------- router: logits, softmax, top2, gates, expert lists ----------------
__global__ __launch_bounds__(256) void router_kernel(
    const float* __restrict__ x3, const float* __restrict__ wrm,
    int* __restrict__ cnt, int* __restrict__ aid, float* __restrict__ gate)
{
    __shared__ float wl[NEXP][DIM];
    const int tid = threadIdx.x;
    for (int i = tid; i < NEXP * DIM / 4; i += 256)
        reinterpret_cast<float4*>(&wl[0][0])[i] = reinterpret_cast<const float4*>(wrm)[i];
    __syncthreads();
    const int w = tid >> 6, lane = tid & 63;
    const int token = blockIdx.x * 4 + w;
    const float* xr = x3 + (size_t)token * DIM;
    float a[NEXP];
#pragma unroll
    for (int e = 0; e < NEXP; e++) a[e] = 0.f;
    for (int d = lane; d < DIM; d += 64) {
        float xv = xr[d];
#pragma unroll
        for (int e = 0; e < NEXP; e++) a[e] += xv * wl[e][d];
    }
#pragma unroll
    for (int e = 0; e < NEXP; e++)
#pragma unroll
        for (int off = 32; off; off >>= 1) a[e] += __shfl_xor(a[e], off);
    if (lane == 0) {
        float m = a[0];
#pragma unroll
        for (int e = 1; e < NEXP; e++) m = fmaxf(m, a[e]);
        float p[NEXP], s = 0.f;
#pragma unroll
        for (int e = 0; e < NEXP; e++) { p[e] = expf(a[e] - m); s += p[e]; }
        float inv = 1.f / s;
#pragma unroll
        for (int e = 0; e < NEXP; e++) p[e] *= inv;
        int i1 = 0; float v1 = p[0];
#pragma unroll
        for (int e = 1; e < NEXP; e++) if (p[e] > v1) { v1 = p[e]; i1 = e; }
        int i2 = -1; float v2 = -1.f;
#pragma unroll
        for (int e = 0; e < NEXP; e++) if (e != i1 && p[e] > v2) { v2 = p[e]; i2 = e; }
        float den = v1 + v2;
        int s1 = atomicAdd(&cnt[i1], 1);
        int s2 = atomicAdd(&cnt[i2], 1);
        aid[i1 * NTOK + s1] = token * 2;
        aid[i2 * NTOK + s2] = token * 2 + 1;
        gate[token * 2]     = v1 / den;
        gate[token * 2 + 1] = v2 / den;
    }
}

// ---------------- expert GEMM1: He[a] = gelu(x3[tok] @ ew1[e] + eb1[e]) ----------------
__global__ __launch_bounds__(256) void egemm1_kernel(
    const half_t* __restrict__ X,   // [NTOK][DIM]
    const half_t* __restrict__ W,   // [E][EHID][DIM]  (transposed)
    const float* __restrict__ eb1,  // [E][EHID]
    const int* __restrict__ cnt, const int* __restrict__ aid,
    half_t* __restrict__ He)        // [2*NTOK][EHID]
{
    const int bid = blockIdx.x;
    const int e = bid >> 9, rem = bid & 511;
    const int mt = rem >> 3, nt = rem & 7;
    const int ne = cnt[e];
    if (mt * 128 >= ne) return;
    __shared__ half_t As[128][40];
    __shared__ half_t Bs[128][40];
    __shared__ int rowmap[128];
    const int tid = threadIdx.x;
    if (tid < 128) {
        int slot = mt * 128 + tid;
        rowmap[tid] = (slot < ne) ? aid[e * NTOK + slot] : -1;
    }
    __syncthreads();
    const int lane = tid & 63, wid = tid >> 6;
    const int wr = wid >> 1, wc = wid & 1;
    const int sm = tid >> 1, sk = (tid & 1) * 16;
    const int arow = rowmap[sm];
    const half_t* Ap = (arow >= 0) ? X + (size_t)(arow >> 1) * DIM + sk : (const half_t*)0;
    const half_t* Bp = W + (size_t)e * EHID * DIM + (size_t)(nt * 128 + sm) * DIM + sk;
    f32x4 acc[4][4];
#pragma unroll
    for (int i = 0; i < 4; i++)
#pragma unroll
        for (int j = 0; j < 4; j++)
#pragma unroll
            for (int q = 0; q < 4; q++) acc[i][j][q] = 0.f;
    const int kk = (lane >> 4) * 8, fr = lane & 15;
    const f16x8 zz = f16x8_zero();
#pragma unroll 1
    for (int k0 = 0; k0 < DIM; k0 += 32) {
        __syncthreads();
        if (Ap) {
            *(f16x8*)&As[sm][sk]     = *(const f16x8*)(Ap + k0);
            *(f16x8*)&As[sm][sk + 8] = *(const f16x8*)(Ap + k0 + 8);
        } else {
            *(f16x8*)&As[sm][sk]     = zz;
            *(f16x8*)&As[sm][sk + 8] = zz;
        }
        *(f16x8*)&Bs[sm][sk]     = *(const f16x8*)(Bp + k0);
        *(f16x8*)&Bs[sm][sk + 8] = *(const f16x8*)(Bp + k0 + 8);
        __syncthreads();
        f16x8 af[4], bf[4];
#pragma unroll
        for (int i = 0; i < 4; i++) af[i] = *(const f16x8*)&As[wr * 64 + i * 16 + fr][kk];
#pragma unroll
        for (int i = 0; i < 4; i++) bf[i] = *(const f16x8*)&Bs[wc * 64 + i * 16 + fr][kk];
#pragma unroll
        for (int i = 0; i < 4; i++)
#pragma unroll
            for (int j = 0; j < 4; j++)
                acc[i][j] = __builtin_amdgcn_mfma_f32_16x16x32_f16(af[i], bf[j], acc[i][j], 0, 0, 0);
    }
    const int rl = (lane >> 4) * 4, cl = lane & 15;
#pragma unroll
    for (int i = 0; i < 4; i++)
#pragma unroll
        for (int q = 0; q < 4; q++) {
            int r = wr * 64 + i * 16 + rl + q;
            int a = rowmap[r];
            if (a >= 0) {
#pragma unroll
                for (int j = 0; j < 4; j++) {
                    int cc = nt * 128 + wc * 64 + j * 16 + cl;
                    float v = acc[i][j][q] + eb1[e * EHID + cc];
                    He[(size_t)a * EHID + cc] = (half_t)gelu_exact(v);
                }
            }
        }
}

// ---------------- expert GEMM2: Ye[a] = (He[a] @ ew2[e] + eb2[e]) * gate[a] ----------------
__global__ __launch_bounds__(256) void egemm2_kernel(
    const half_t* __restrict__ Hin,  // [2*NTOK][EHID]
    const half_t* __restrict__ W,    // [E][DIM][EHID]  (transposed)
    const float* __restrict__ eb2,   // [E][DIM]
    const int* __restrict__ cnt, const int* __restrict__ aid,
    const float* __restrict__ gate,
    float* __restrict__ Ye)          // [2*NTOK][DIM]
{
    const int bid = blockIdx.x;
    const int e = bid >> 8, rem = bid & 255;
    const int mt = rem >> 2, nt = rem & 3;
    const int ne = cnt[e];
    if (mt * 128 >= ne) return;
    __shared__ half_t As[128][40];
    __shared__ half_t Bs[128][40];
    __shared__ int rowmap[128];
    const int tid = threadIdx.x;
    if (tid < 128) {
        int slot = mt * 128 + tid;
        rowmap[tid] = (slot < ne) ? aid[e * NTOK + slot] : -1;
    }
    __syncthreads();
    const int lane = tid & 63, wid = tid >> 6;
    const int wr = wid >> 1, wc = wid & 1;
    const int sm = tid >> 1, sk = (tid & 1) * 16;
    const int arow = rowmap[sm];
    const half_t* Ap = (arow >= 0) ? Hin + (size_t)arow * EHID + sk : (const half_t*)0;
    const half_t* Bp = W + (size_t)e * DIM * EHID + (size_t)(nt * 128 + sm) * EHID + sk;
    f32x4 acc[4][4];
#pragma unroll
    for (int i = 0; i < 4; i++)
#pragma unroll
        for (int j = 0; j < 4; j++)
#pragma unroll
            for (int q = 0; q < 4; q++) acc[i][j][q] = 0.f;
    const int kk = (lane >> 4) * 8, fr = lane & 15;
    const f16x8 zz = f16x8_zero();
#pragma unroll 1
    for (int k0 = 0; k0 < EHID; k0 += 32) {
        __syncthreads();
        if (Ap) {
            *(f16x8*)&As[sm][sk]     = *(const f16x8*)(Ap + k0);
            *(f16x8*)&As[sm][sk + 8] = *(const f16x8*)(Ap + k0 + 8);
        } else {
            *(f16x8*)&As[sm][sk]     = zz;
            *(f16x8*)&As[sm][sk + 8] = zz;
        }
        *(f16x8*)&Bs[sm][sk]     = *(const f16x8*)(Bp + k0);
        *(f16x8*)&Bs[sm][sk + 8] = *(const f16x8*)(Bp + k0 + 8);
        __syncthreads();
        f16x8 af[4], bf[4];
#pragma unroll
        for (int i = 0; i < 4; i++) af[i] = *(const f16x8*)&As[wr * 64 + i * 16 + fr][kk];
#pragma unroll
        for (int i = 0; i < 4; i++) bf[i] = *(const f16x8*)&Bs[wc * 64 + i * 16 + fr][kk];
#pragma unroll
        for (int i = 0; i < 4; i++)
#pragma unroll
            for (int j = 0; j < 4; j++)
                acc[i][j] = __builtin_amdgcn_mfma_f32_16x16x32_f16(af[i], bf[j], acc[i][j], 0, 0, 0);
    }
    const int rl = (lane >> 4) * 4, cl = lane & 15;
#pragma unroll
    for (int i = 0; i < 4; i++)
#pragma unroll
        for (int q = 0; q < 4; q++) {
            int r = wr * 64 + i * 16 + rl + q;
            int a = rowmap[r];
            if (a >= 0) {
                float gv = gate[a];
#pragma unroll
                for (int j = 0; j < 4; j++) {
                    int cc = nt * 128 + wc * 64 + j * 16 + cl;
                    float v = (acc[i][j][q] + eb2[e * DIM + cc]) * gv;
                    Ye[(size_t)a * DIM + cc] = v;
                }
            }
        }
}

// ---------------- combine two expert outputs per token + final LN ----------------
__global__ __launch_bounds__(256) void combine_lnf_kernel(
    const float* __restrict__ Ye, const float* __restrict__ g, const float* __restrict__ b,
    float* __restrict__ out)
{
    const int t = blockIdx.x, tid = threadIdx.x;
    __shared__ float red[4];
    float2 y0 = reinterpret_cast<const float2*>(Ye + (size_t)(2 * t) * DIM)[tid];
    float2 y1 = reinterpret_cast<const float2*>(Ye + (size_t)(2 * t + 1) * DIM)[tid];
    float z0 = y0.x + y1.x, z1 = y0.y + y1.y;
    float mean = block_sum4(z0 + z1, red, tid) * (1.0f / DIM);
    float d0 = z0 - mean, d1 = z1 - mean;
    float var = block_sum4(d0 * d0 + d1 * d1, red, tid) * (1.0f / DIM);
    float rstd = rsqrtf(var + 1e-5f);
    int d = tid * 2;
    out[(size_t)t * DIM + d]     = d0 * rstd * g[d]     + b[d];
    out[(size_t)t * DIM + d + 1] = d1 * rstd * g[d + 1] + b[d + 1];
    if (t == 0 && tid == 0) out[(size_t)NTOK * DIM] = 0.f;  // aux_loss
}

__global__ void zero_cnt_kernel(int* cnt) {
    if (threadIdx.x < NEXP) cnt[threadIdx.x] = 0;
}

extern "C" void kernel_launch(void* const* d_in, const int* in_sizes, int n_in,
                              void* d_out, int out_size, void* d_ws, size_t ws_size,
                              hipStream_t stream)
{
    (void)in_sizes; (void)n_in; (void)out_size; (void)ws_size;
    const float* x    = (const float*)d_in[0];
    const float* ln1g = (const float*)d_in[1];
    const float* ln1b = (const float*)d_in[2];
    const float* w1   = (const float*)d_in[3];
    const float* b1   = (const float*)d_in[4];
    const float* w2   = (const float*)d_in[5];
    const float* b2   = (const float*)d_in[6];
    const float* ln2g = (const float*)d_in[7];
    const float* ln2b = (const float*)d_in[8];
    const float* wrm  = (const float*)d_in[9];
    const float* ew1  = (const float*)d_in[10];
    const float* eb1  = (const float*)d_in[11];
    const float* ew2  = (const float*)d_in[12];
    const float* eb2  = (const float*)d_in[13];
    const float* lnfg = (const float*)d_in[14];
    const float* lnfb = (const float*)d_in[15];
    float* out = (float*)d_out;

    char* w = (char*)d_ws;
    size_t off = 0;
    auto take = [&](size_t bytes) {
        char* p = w + off;
        off += bytes;
        off = (off + 255) & ~(size_t)255;
        return p;
    };
    half_t* xh_h  = (half_t*)take((size_t)NTOK * DIM * 2);
    half_t* xh_l  = (half_t*)take((size_t)NTOK * DIM * 2);
    half_t* w1t_h = (half_t*)take((size_t)DIM * MHID * 2);
    half_t* w1t_l = (half_t*)take((size_t)DIM * MHID * 2);
    half_t* w2t_h = (half_t*)take((size_t)MHID * DIM * 2);
    half_t* w2t_l = (half_t*)take((size_t)MHID * DIM * 2);
    char*   big   = take((size_t)NTOK * MHID * 2 * 2);        // 64 MiB: a1 hi/lo, later He + Ye
    half_t* a1h   = (half_t*)big;
    half_t* a1l   = (half_t*)(big + (size_t)NTOK * MHID * 2);
    half_t* heh   = (half_t*)big;                              // alias (a1 dead after gemm2)
    float*  yef   = (float*)(big + (size_t)NTOK * MHID * 2);   // alias
    float*  x3f   = (float*)take((size_t)NTOK * DIM * 4);      // h buffer, then x3 f32
    half_t* x3h   = (half_t*)take((size_t)NTOK * DIM * 2);
    half_t* ew1t  = (half_t*)take((size_t)NEXP * DIM * EHID * 2);
    half_t* ew2t  = (half_t*)take((size_t)NEXP * EHID * DIM * 2);
    int*    cnt   = (int*)take(256);
    int*    aid   = (int*)take((size_t)NEXP * NTOK * 4);
    float*  gate  = (float*)take((size_t)NTOK * 2 * 4);

    zero_cnt_kernel<<<1, 64, 0, stream>>>(cnt);
    ln1_split_kernel<<<NTOK, 256, 0, stream>>>(x, ln1g, ln1b, xh_h, xh_l);
    transpose_split_kernel<<<dim3(MHID / 32, DIM / 32, 1), dim3(32, 8), 0, stream>>>(w1, w1t_h, w1t_l, DIM, MHID);
    transpose_split_kernel<<<dim3(DIM / 32, MHID / 32, 1), dim3(32, 8), 0, stream>>>(w2, w2t_h, w2t_l, MHID, DIM);
    transpose_split_kernel<<<dim3(EHID / 32, DIM / 32, NEXP), dim3(32, 8), 0, stream>>>(ew1, ew1t, (half_t*)0, DIM, EHID);
    transpose_split_kernel<<<dim3(DIM / 32, EHID / 32, NEXP), dim3(32, 8), 0, stream>>>(ew2, ew2t, (half_t*)0, EHID, DIM);
    gemm3_kernel<1><<<dim3(NTOK / 128, MHID / 128), 256, 0, stream>>>(
        xh_h, xh_l, w1t_h, w1t_l, b1, (float*)0, a1h, a1l, NTOK, MHID, DIM);
    gemm3_kernel<0><<<dim3(NTOK / 128, DIM / 128), 256, 0, stream>>>(
        a1h, a1l, w2t_h, w2t_l, b2, x3f, (half_t*)0, (half_t*)0, NTOK, DIM, MHID);
    resid_ln2_kernel<<<NTOK, 256, 0, stream>>>(x, x3f, ln2g, ln2b, x3h);
    router_kernel<<<NTOK / 4, 256, 0, stream>>>(x3f, wrm, cnt, aid, gate);
    egemm1_kernel<<<NEXP * (NTOK / 128) * (EHID / 128), 256, 0, stream>>>(x3h, ew1t, eb1, cnt, aid, heh);
    egemm2_kernel<<<NEXP * (NTOK / 128) * (DIM / 128), 256, 0, stream>>>(heh, ew2t, eb2, cnt, aid, gate, yef);
    combine_lnf_kernel<<<NTOK, 256, 0, stream>>>(yef, lnfg, lnfb, out);
}